// Round 2
// baseline (563.423 us; speedup 1.0000x reference)
//
#include <hip/hip_runtime.h>
#include <hip/hip_bf16.h>

typedef unsigned short u16;
typedef unsigned int u32;
typedef __attribute__((ext_vector_type(8))) short short8;
typedef __attribute__((ext_vector_type(4))) float f32x4;

#define B_   512   // batch (i and j)
#define C_   256   // channel dim (reduction c)
#define HID_ 512   // MLP hidden
#define HW_  256   // h*w (k)

__device__ __forceinline__ u16 f2b(float f) {
    union { float f; u32 i; } v; v.f = f;
    u32 x = v.i;
    u32 r = (x + 0x7fffu + ((x >> 16) & 1u)) >> 16;
    return (u16)r;
}
__device__ __forceinline__ float b2f(u16 u) {
    union { u32 i; float f; } v; v.i = ((u32)u) << 16; return v.f;
}

// ---------------------------------------------------------------------------
// K1: pred = (anchor + MLP(anchor)) @ Wc   -> bf16 [512][256]
// 4 rows per block (weights reuse), fp32 math. Grid 128 x 256.
// ---------------------------------------------------------------------------
__global__ __launch_bounds__(256) void k_mlp(
        const float* __restrict__ anchor, const float* __restrict__ W1,
        const float* __restrict__ b1, const float* __restrict__ W2,
        const float* __restrict__ b2, const float* __restrict__ Wc,
        u16* __restrict__ pred)
{
    const int row0 = blockIdx.x * 4, t = threadIdx.x;
    __shared__ float a_sh[4][C_];
    __shared__ float h_sh[4][HID_];
    __shared__ float a2_sh[4][C_];

    #pragma unroll
    for (int r = 0; r < 4; ++r) a_sh[r][t] = anchor[(size_t)(row0 + r) * C_ + t];
    __syncthreads();

    float h0[4], h1[4];
    {
        float2 bb = *(const float2*)&b1[2 * t];
        #pragma unroll
        for (int r = 0; r < 4; ++r) { h0[r] = bb.x; h1[r] = bb.y; }
    }
    for (int l = 0; l < C_; ++l) {
        float2 w = *(const float2*)&W1[(size_t)l * HID_ + 2 * t];
        #pragma unroll
        for (int r = 0; r < 4; ++r) {
            float a = a_sh[r][l];
            h0[r] += a * w.x;
            h1[r] += a * w.y;
        }
    }
    #pragma unroll
    for (int r = 0; r < 4; ++r) {
        h_sh[r][2 * t]     = fmaxf(h0[r], 0.f);
        h_sh[r][2 * t + 1] = fmaxf(h1[r], 0.f);
    }
    __syncthreads();

    float a2[4];
    {
        float bv = b2[t];
        #pragma unroll
        for (int r = 0; r < 4; ++r) a2[r] = a_sh[r][t] + bv;
    }
    for (int h = 0; h < HID_; ++h) {
        float w = W2[(size_t)h * C_ + t];
        #pragma unroll
        for (int r = 0; r < 4; ++r) a2[r] += h_sh[r][h] * w;
    }
    #pragma unroll
    for (int r = 0; r < 4; ++r) a2_sh[r][t] = a2[r];
    __syncthreads();

    float p[4] = {0.f, 0.f, 0.f, 0.f};
    for (int d = 0; d < C_; ++d) {
        float w = Wc[(size_t)d * C_ + t];
        #pragma unroll
        for (int r = 0; r < 4; ++r) p[r] += a2_sh[r][d] * w;
    }
    #pragma unroll
    for (int r = 0; r < 4; ++r) pred[(size_t)(row0 + r) * C_ + t] = f2b(p[r]);
}

// ---------------------------------------------------------------------------
// K2: ws2[j][k_][i] = sum_c positive[j][c][k_] * pred[i][c]   (bf16 out)
// block: one (j, k-half): 128k x 512i, 512 threads (8 waves of 64k? no:
// wave = 64k x 128i, wk = w&1, wi = w>>1). c staged in 2 chunks of 128.
// A staged f32->bf16 transposed into LDS with XOR-oct swizzle (conflict-free
// both on staging writes [lane k-stride 32] and b128 frag reads).
// ---------------------------------------------------------------------------
__global__ __launch_bounds__(512) void k_einsum(
        const float* __restrict__ positive, const u16* __restrict__ pred,
        u16* __restrict__ ws2)
{
    const int bx = blockIdx.x;
    const int kt = bx & 1;         // k half
    const int j  = bx >> 1;        // 0..511
    const int k0 = kt * 128;

    const int tid  = threadIdx.x;
    const int lane = tid & 63, w = tid >> 6;
    const int q = lane >> 4, m = lane & 15;
    const int wk = w & 1, wi = w >> 1;       // wave: k = wk*64.., i = wi*128..

    // At[kl][oct'] : kl in [0,128), 16 octets of 8 c (bf16x8 = uint4)
    __shared__ uint4 At[128 * 16];           // 32 KB

    const float* pos_j = positive + (size_t)j * (C_ * HW_);

    f32x4 acc[4][8];
    #pragma unroll
    for (int a = 0; a < 4; ++a)
        #pragma unroll
        for (int b = 0; b < 8; ++b) acc[a][b] = f32x4{0.f, 0.f, 0.f, 0.f};

    // staging ids: co = c-octet (0..15), ko = k lane (0..31)
    const int co = tid >> 5, ko = tid & 31;

    for (int c0 = 0; c0 < C_; c0 += 128) {
        // ---- stage: positive[j, c0..c0+128, k0..k0+128] -> bf16 transposed
        {
            u32 pk[4][4];  // [kkk][c-pair]
            const float* base = pos_j + (size_t)(c0 + co * 8) * HW_ + k0 + ko;
            #pragma unroll
            for (int cr = 0; cr < 8; ++cr) {
                #pragma unroll
                for (int kkk = 0; kkk < 4; ++kkk) {
                    u16 b = f2b(base[(size_t)cr * HW_ + kkk * 32]);
                    if ((cr & 1) == 0) pk[kkk][cr >> 1] = (u32)b;
                    else               pk[kkk][cr >> 1] |= ((u32)b) << 16;
                }
            }
            #pragma unroll
            for (int kkk = 0; kkk < 4; ++kkk) {
                const int kl = ko + kkk * 32;
                uint4 o; o.x = pk[kkk][0]; o.y = pk[kkk][1];
                o.z = pk[kkk][2]; o.w = pk[kkk][3];
                At[kl * 16 + (co ^ (kl & 15))] = o;
            }
        }
        __syncthreads();

        // ---- compute: 4 k-steps of 32 c
        #pragma unroll
        for (int s = 0; s < 4; ++s) {
            union { uint4 u; short8 v; } af[4], bf;
            #pragma unroll
            for (int mt = 0; mt < 4; ++mt) {
                const int kl = wk * 64 + mt * 16 + m;
                af[mt].u = At[kl * 16 + ((s * 4 + q) ^ (kl & 15))];
            }
            #pragma unroll
            for (int nt = 0; nt < 8; ++nt) {
                const int i_ = wi * 128 + nt * 16 + m;
                bf.u = *(const uint4*)&pred[(size_t)i_ * C_ + c0 + s * 32 + q * 8];
                #pragma unroll
                for (int mt = 0; mt < 4; ++mt)
                    acc[mt][nt] = __builtin_amdgcn_mfma_f32_16x16x32_bf16(
                        af[mt].v, bf.v, acc[mt][nt], 0, 0, 0);
            }
        }
        __syncthreads();
    }

    // ---- store ws2[j][k_][i]; D: col(lane&15)=i, row(q*4+r)=k_
    #pragma unroll
    for (int mt = 0; mt < 4; ++mt) {
        #pragma unroll
        for (int nt = 0; nt < 8; ++nt) {
            const int i_ = wi * 128 + nt * 16 + m;
            #pragma unroll
            for (int r = 0; r < 4; ++r) {
                const int k_ = k0 + wk * 64 + mt * 16 + q * 4 + r;
                ws2[((size_t)j * HW_ + k_) * B_ + i_] = f2b(acc[mt][nt][r]);
            }
        }
    }
}

// ---------------------------------------------------------------------------
// K3: out[k][i][j] = ws2[j][k][i] - max_j ws2[j][k][i]    (f32 out)
// block: one k, 64 i, all 512 j resident in LDS (single HBM pass).
// ---------------------------------------------------------------------------
__global__ __launch_bounds__(256) void k_maxsub(
        const u16* __restrict__ ws2, float* __restrict__ out)
{
    const int bx = blockIdx.x;
    const int k  = bx >> 3;
    const int i0 = (bx & 7) * 64;
    const int t  = threadIdx.x;

    __shared__ u16 tile[512 * 66];     // [j][i] pitch 66 (u32-aligned rows)
    __shared__ float maxp[4][64];
    __shared__ float maxv[64];

    // ---- fill: 8 rows per pass, u32 (2 i) per lane
    {
        const int jr = t >> 5, lane5 = t & 31;
        for (int p = 0; p < 64; ++p) {
            const int jj = p * 8 + jr;
            u32 v = *(const u32*)&ws2[((size_t)jj * HW_ + k) * B_ + i0 + lane5 * 2];
            *(u32*)&tile[jj * 66 + lane5 * 2] = v;
        }
    }
    __syncthreads();

    // ---- max over j
    {
        const int i = t & 63, jq = t >> 6;
        float pm = -3.4e38f;
        for (int r = 0; r < 128; ++r) {
            const int jj = jq * 128 + r;
            pm = fmaxf(pm, b2f(tile[jj * 66 + i]));
        }
        maxp[jq][i] = pm;
    }
    __syncthreads();
    if (t < 64)
        maxv[t] = fmaxf(fmaxf(maxp[0][t], maxp[1][t]),
                        fmaxf(maxp[2][t], maxp[3][t]));
    __syncthreads();

    // ---- subtract + transposed store (lanes j-contiguous, conflict-free)
    {
        const int ir = t >> 5, jr = t & 31;
        #pragma unroll
        for (int p = 0; p < 8; ++p) {
            const int i_loc = p * 8 + ir;
            const float mv = maxv[i_loc];
            float* orow = out + ((size_t)k * B_ + i0 + i_loc) * B_;
            #pragma unroll
            for (int c = 0; c < 16; ++c) {
                const int jj = c * 32 + jr;
                orow[jj] = b2f(tile[jj * 66 + i_loc]) - mv;
            }
        }
    }
}

// ---------------------------------------------------------------------------
extern "C" void kernel_launch(void* const* d_in, const int* in_sizes, int n_in,
                              void* d_out, int out_size, void* d_ws, size_t ws_size,
                              hipStream_t stream)
{
    const float* anchor   = (const float*)d_in[0];
    const float* positive = (const float*)d_in[1];
    const float* W1 = (const float*)d_in[2];
    const float* b1 = (const float*)d_in[3];
    const float* W2 = (const float*)d_in[4];
    const float* b2 = (const float*)d_in[5];
    const float* Wc = (const float*)d_in[6];
    float* out = (float*)d_out;

    u16* pred = (u16*)d_ws;                                   // 256 KB
    u16* ws2  = (u16*)((char*)d_ws + (size_t)B_ * C_ * 2);    // 134 MB [j][k][i]

    k_mlp<<<B_ / 4, 256, 0, stream>>>(anchor, W1, b1, W2, b2, Wc, pred);
    k_einsum<<<B_ * 2, 512, 0, stream>>>(positive, pred, ws2);
    k_maxsub<<<HW_ * 8, 256, 0, stream>>>(ws2, out);
}

// Round 3
// 505.687 us; speedup vs baseline: 1.1142x; 1.1142x over previous
//
#include <hip/hip_runtime.h>
#include <hip/hip_bf16.h>

typedef unsigned short u16;
typedef unsigned int u32;
typedef __attribute__((ext_vector_type(8))) short short8;
typedef __attribute__((ext_vector_type(4))) float f32x4;

#define B_   512   // batch (i and j)
#define C_   256   // channel dim (reduction c)
#define HID_ 512   // MLP hidden
#define HW_  256   // h*w (k)

__device__ __forceinline__ u16 f2b(float f) {
    union { float f; u32 i; } v; v.f = f;
    u32 x = v.i;
    u32 r = (x + 0x7fffu + ((x >> 16) & 1u)) >> 16;
    return (u16)r;
}
__device__ __forceinline__ float b2f(u16 u) {
    union { u32 i; float f; } v; v.i = ((u32)u) << 16; return v.f;
}

// async global->LDS, 16 B per lane; LDS dest = wave-uniform base + lane*16
__device__ __forceinline__ void dma16(const u16* g, u16* l) {
    __builtin_amdgcn_global_load_lds(
        (const __attribute__((address_space(1))) u32*)g,
        (__attribute__((address_space(3))) u32*)l, 16, 0, 0);
}

// ---------------------------------------------------------------------------
// K1: pred = (anchor + MLP(anchor)) @ Wc   -> bf16 [512][256]
// ---------------------------------------------------------------------------
__global__ __launch_bounds__(256) void k_mlp(
        const float* __restrict__ anchor, const float* __restrict__ W1,
        const float* __restrict__ b1, const float* __restrict__ W2,
        const float* __restrict__ b2, const float* __restrict__ Wc,
        u16* __restrict__ pred)
{
    const int row0 = blockIdx.x * 4, t = threadIdx.x;
    __shared__ float a_sh[4][C_];
    __shared__ float h_sh[4][HID_];
    __shared__ float a2_sh[4][C_];

    #pragma unroll
    for (int r = 0; r < 4; ++r) a_sh[r][t] = anchor[(size_t)(row0 + r) * C_ + t];
    __syncthreads();

    float h0[4], h1[4];
    {
        float2 bb = *(const float2*)&b1[2 * t];
        #pragma unroll
        for (int r = 0; r < 4; ++r) { h0[r] = bb.x; h1[r] = bb.y; }
    }
    for (int l = 0; l < C_; ++l) {
        float2 w = *(const float2*)&W1[(size_t)l * HID_ + 2 * t];
        #pragma unroll
        for (int r = 0; r < 4; ++r) {
            float a = a_sh[r][l];
            h0[r] += a * w.x;
            h1[r] += a * w.y;
        }
    }
    #pragma unroll
    for (int r = 0; r < 4; ++r) {
        h_sh[r][2 * t]     = fmaxf(h0[r], 0.f);
        h_sh[r][2 * t + 1] = fmaxf(h1[r], 0.f);
    }
    __syncthreads();

    float a2[4];
    {
        float bv = b2[t];
        #pragma unroll
        for (int r = 0; r < 4; ++r) a2[r] = a_sh[r][t] + bv;
    }
    for (int h = 0; h < HID_; ++h) {
        float w = W2[(size_t)h * C_ + t];
        #pragma unroll
        for (int r = 0; r < 4; ++r) a2[r] += h_sh[r][h] * w;
    }
    #pragma unroll
    for (int r = 0; r < 4; ++r) a2_sh[r][t] = a2[r];
    __syncthreads();

    float p[4] = {0.f, 0.f, 0.f, 0.f};
    for (int d = 0; d < C_; ++d) {
        float w = Wc[(size_t)d * C_ + t];
        #pragma unroll
        for (int r = 0; r < 4; ++r) p[r] += a2_sh[r][d] * w;
    }
    #pragma unroll
    for (int r = 0; r < 4; ++r) pred[(size_t)(row0 + r) * C_ + t] = f2b(p[r]);
}

// ---------------------------------------------------------------------------
// KT: P[k][j][c] (bf16) = positive[j][c][k] (f32)
// block: one j, k-tile 64; 4 passes of 64 c through an f32 LDS tile.
// ---------------------------------------------------------------------------
__global__ __launch_bounds__(256) void k_transpose(
        const float* __restrict__ positive, u16* __restrict__ P)
{
    const int bx = blockIdx.x;
    const int j  = bx >> 2;
    const int k0 = (bx & 3) * 64;
    const int t  = threadIdx.x;

    __shared__ float Tf[64][68];   // [c_local][k_local], pitch 68

    const float* pj = positive + (size_t)j * (C_ * HW_);

    for (int p = 0; p < 4; ++p) {
        const int c0 = p * 64;
        // load: 16 threads per c-row (float4 each), 16 rows per step
        {
            const int kk = t & 15, cr = t >> 4;
            #pragma unroll
            for (int s = 0; s < 4; ++s) {
                const int cl = s * 16 + cr;
                float4 v = *(const float4*)&pj[(size_t)(c0 + cl) * HW_ + k0 + kk * 4];
                *(float4*)&Tf[cl][kk * 4] = v;
            }
        }
        __syncthreads();
        // store: thread -> one k row (kr), 16 c each; pack to 2 uint4
        {
            const int kr = t >> 2, cq = t & 3;
            u32 wpk[8];
            #pragma unroll
            for (int y = 0; y < 16; y += 2) {
                u16 lo = f2b(Tf[cq * 16 + y][kr]);
                u16 hi = f2b(Tf[cq * 16 + y + 1][kr]);
                wpk[y >> 1] = (u32)lo | ((u32)hi << 16);
            }
            u16* dst = P + ((size_t)(k0 + kr) * B_ + j) * C_ + c0 + cq * 16;
            ((uint4*)dst)[0] = make_uint4(wpk[0], wpk[1], wpk[2], wpk[3]);
            ((uint4*)dst)[1] = make_uint4(wpk[4], wpk[5], wpk[6], wpk[7]);
        }
        __syncthreads();
    }
}

// ---------------------------------------------------------------------------
// KG: fused GEMM + row-max + subtract.
// block = (k, i-tile 128), 512 threads / 8 waves (wi 0..1 x wj 0..3).
// out[k][i][j] = logits - max_j logits, logits = sum_c pred[i][c]*P[k][j][c].
// A and B staged per 32-c chunk via global_load_lds (16B/lane).
// ---------------------------------------------------------------------------
__global__ __launch_bounds__(512, 2) void k_gemm_fused(
        const u16* __restrict__ P, const u16* __restrict__ pred,
        float* __restrict__ out)
{
    const int bx = blockIdx.x;
    const int k  = bx >> 2;
    const int i0 = (bx & 3) * 128;

    // B: slot = j*4 + oct (uint4 granules), 512 j x 4 oct = 32 KB
    __shared__ u16 Bsm[B_ * 32];
    // A: slot = i*4 + oct, 128 i x 4 oct = 8 KB
    __shared__ u16 Asm[128 * 32];
    __shared__ float maxw[128][4];
    __shared__ float maxv[128];

    const int tid  = threadIdx.x;
    const int lane = tid & 63, w = tid >> 6;
    const int q = lane >> 4, m = lane & 15;
    const int wi = w >> 2, wj = w & 3;

    const u16* Pk = P + (size_t)k * (B_ * C_);

    f32x4 acc[4][8];
    #pragma unroll
    for (int a = 0; a < 4; ++a)
        #pragma unroll
        for (int b = 0; b < 8; ++b) acc[a][b] = f32x4{0.f, 0.f, 0.f, 0.f};

    for (int ch = 0; ch < 8; ++ch) {
        const int c0 = ch * 32;
        __syncthreads();   // previous chunk's frag reads complete
        // DMA B chunk: wave w, round r: slots w*256 + r*64 + lane
        //   slot S -> j = S>>2, oct = S&3 ; 16 j-rows x 64 B per instr
        #pragma unroll
        for (int r = 0; r < 4; ++r) {
            const int jb  = w * 64 + r * 16 + (lane >> 2);
            const int oct = lane & 3;
            dma16(Pk + (size_t)jb * C_ + c0 + oct * 8,
                  Bsm + (size_t)(w * 256 + r * 64) * 8);
        }
        // DMA A chunk: slots w*64 + lane -> i = S>>2, oct = S&3
        {
            const int ia  = w * 16 + (lane >> 2);
            const int oct = lane & 3;
            dma16(pred + (size_t)(i0 + ia) * C_ + c0 + oct * 8,
                  Asm + (size_t)(w * 64) * 8);
        }
        __syncthreads();   // drains vmcnt -> LDS data visible

        union { uint4 u; short8 v; } af[4], bf[8];
        #pragma unroll
        for (int mt = 0; mt < 4; ++mt)
            af[mt].u = *(const uint4*)&Asm[((wi * 64 + mt * 16 + m) * 4 + q) * 8];
        #pragma unroll
        for (int nt = 0; nt < 8; ++nt)
            bf[nt].u = *(const uint4*)&Bsm[((wj * 128 + nt * 16 + m) * 4 + q) * 8];
        #pragma unroll
        for (int mt = 0; mt < 4; ++mt)
            #pragma unroll
            for (int nt = 0; nt < 8; ++nt)
                acc[mt][nt] = __builtin_amdgcn_mfma_f32_16x16x32_bf16(
                    af[mt].v, bf[nt].v, acc[mt][nt], 0, 0, 0);
    }

    // ---- epilogue: row-max over j, subtract, store out[k][i][j]
    float pm[4][4];
    #pragma unroll
    for (int mt = 0; mt < 4; ++mt)
        #pragma unroll
        for (int r = 0; r < 4; ++r) {
            float v = acc[mt][0][r];
            #pragma unroll
            for (int nt = 1; nt < 8; ++nt) v = fmaxf(v, acc[mt][nt][r]);
            pm[mt][r] = v;
        }
    #pragma unroll
    for (int d = 1; d < 16; d <<= 1) {
        #pragma unroll
        for (int mt = 0; mt < 4; ++mt)
            #pragma unroll
            for (int r = 0; r < 4; ++r)
                pm[mt][r] = fmaxf(pm[mt][r], __shfl_xor(pm[mt][r], d, 64));
    }
    __syncthreads();   // Bsm/Asm reads done (also orders maxw writes)
    if (m == 0) {
        #pragma unroll
        for (int mt = 0; mt < 4; ++mt)
            #pragma unroll
            for (int r = 0; r < 4; ++r)
                maxw[wi * 64 + mt * 16 + q * 4 + r][wj] = pm[mt][r];
    }
    __syncthreads();
    if (tid < 128)
        maxv[tid] = fmaxf(fmaxf(maxw[tid][0], maxw[tid][1]),
                          fmaxf(maxw[tid][2], maxw[tid][3]));
    __syncthreads();

    #pragma unroll
    for (int mt = 0; mt < 4; ++mt) {
        #pragma unroll
        for (int r = 0; r < 4; ++r) {
            const int i_ = i0 + wi * 64 + mt * 16 + q * 4 + r;
            const float mv = maxv[wi * 64 + mt * 16 + q * 4 + r];
            float* orow = out + ((size_t)k * B_ + i_) * B_ + wj * 128;
            #pragma unroll
            for (int nt = 0; nt < 8; ++nt)
                orow[nt * 16 + m] = acc[mt][nt][r] - mv;
        }
    }
}

// ---------------------------------------------------------------------------
extern "C" void kernel_launch(void* const* d_in, const int* in_sizes, int n_in,
                              void* d_out, int out_size, void* d_ws, size_t ws_size,
                              hipStream_t stream)
{
    const float* anchor   = (const float*)d_in[0];
    const float* positive = (const float*)d_in[1];
    const float* W1 = (const float*)d_in[2];
    const float* b1 = (const float*)d_in[3];
    const float* W2 = (const float*)d_in[4];
    const float* b2 = (const float*)d_in[5];
    const float* Wc = (const float*)d_in[6];
    float* out = (float*)d_out;

    u16* pred = (u16*)d_ws;                                   // 256 KB
    u16* P    = (u16*)((char*)d_ws + (size_t)B_ * C_ * 2);    // 67 MB [k][j][c] bf16

    k_mlp<<<B_ / 4, 256, 0, stream>>>(anchor, W1, b1, W2, b2, Wc, pred);
    k_transpose<<<B_ * 4, 256, 0, stream>>>(positive, P);
    k_gemm_fused<<<HW_ * 4, 512, 0, stream>>>(P, pred, out);
}